// Round 7
// baseline (96612.372 us; speedup 1.0000x reference)
//
#include <hip/hip_runtime.h>
#include <hip/hip_bf16.h>

// HyperGANUpBlock: x[4,8,32,32,128] -> upsample x2 (nearest) -> conv3x3x3 (per-sample
// w1[4,3,3,3,128,64], SAME, correlation) -> BN(train, eps=1e-3) -> ReLU
// -> concat skip[4,16,64,64,64] -> conv3x3x3 (per-sample w2) -> BN -> ReLU.
// ROWS = 4*16*64*64 = 262144 voxels, 64 channels; out = 16,777,216 elements.
//
// R7: dtype-adaptive. Inputs probed on device (gamma1[0] word): fp32 (reference native)
// or bf16. OUTPUT dtype follows the input dtype — all prior rounds wrote bf16 into what
// is almost certainly an fp32 buffer (explains byte-identical absmax across 6 rounds:
// upper half of d_out never written -> absmax == max|ref| exactly, deterministically).
// Phases (single kernel, stub symbol name):
//   0 init stats+flag | 1 conv1->y1(bf16,ws) | 2 stats(y1) | 3 finalize BN1
//   4 bn+relu y1      | 5 conv2->out(dtype)  | 6 stats(out)| 7 finalize BN2
//   8 bn+relu out (or fp32 sentinel 0.25/0.75)
// ws: [0,32MiB) y1 bf16 ; +32MiB float stats[256] ; +32MiB+1KiB int flag.

__device__ __forceinline__ float ldin(const void* p, unsigned long long i, int f32) {
  if (f32) return ((const float*)p)[i];
  return __bfloat162float(((const __hip_bfloat16*)p)[i]);
}
__device__ __forceinline__ void stout(void* p, unsigned long long i, float v, int f32) {
  if (f32) ((float*)p)[i] = v;
  else ((__hip_bfloat16*)p)[i] = __float2bfloat16(v);
}

extern "C" __global__ void HyperGANUpBlock_47287589929740_kernel(
    int phase, int force,
    const void* x, const void* w1, const void* w2, const void* skip,
    const void* g1, const void* b1, const void* g2, const void* b2,
    __hip_bfloat16* y1, void* out, float* stats, int* flag) {
  int tid = threadIdx.x;
  int gid = blockIdx.x * blockDim.x + tid;

  if (phase == 0) {  // init: zero stats, probe dtype from gamma1[0] word
    if (tid < 256) stats[tid] = 0.f;
    if (tid == 0) {
      int f;
      if (force) {
        f = force;
      } else {
        const unsigned short* gw = (const unsigned short*)g1;
        if (gw[0] == 0x3F80u && gw[1] == 0x3F80u)      f = 0;  // bf16 ones pair
        else if (gw[0] == 0x0000u && gw[1] == 0x3F80u) f = 1;  // fp32 1.0 little-endian
        else                                           f = 2;  // unknown
      }
      *flag = f;
    }
    return;
  }

  int fl = *flag;

  if (phase == 1 || phase == 5) {  // conv: 16384 blocks x 256 threads
    if (fl >= 2) return;
    int f32 = fl;
    int c0 = (gid & 15) << 2;      // 4 output channels per thread
    int s  = gid >> 4;             // voxel 0..262143
    int ow = s & 63;
    int oh = (s >> 6) & 63;
    int od = (s >> 12) & 15;
    int b  = s >> 16;
    float a0 = 0.f, a1 = 0.f, a2 = 0.f, a3 = 0.f;
    const void* w = (phase == 1) ? w1 : w2;
    unsigned long long wb = (unsigned long long)b * 27ull * 8192ull;
    for (int kd = 0; kd < 3; ++kd) {
      int ud = od + kd - 1;
      if (ud < 0 || ud >= 16) continue;
      for (int kh = 0; kh < 3; ++kh) {
        int uh = oh + kh - 1;
        if (uh < 0 || uh >= 64) continue;
        for (int kw = 0; kw < 3; ++kw) {
          int uw = ow + kw - 1;
          if (uw < 0 || uw >= 64) continue;
          unsigned long long wp =
              wb + (unsigned long long)((kd * 3 + kh) * 3 + kw) * 8192ull + c0;
          if (phase == 1) {
            unsigned long long ip =
                (unsigned long long)((((b * 8 + (ud >> 1)) * 32 + (uh >> 1)) * 32) +
                                     (uw >> 1)) * 128ull;
            for (int ci = 0; ci < 128; ++ci) {
              float xf = ldin(x, ip + ci, f32);
              unsigned long long wo = wp + (unsigned long long)ci * 64ull;
              a0 += xf * ldin(w, wo, f32);
              a1 += xf * ldin(w, wo + 1, f32);
              a2 += xf * ldin(w, wo + 2, f32);
              a3 += xf * ldin(w, wo + 3, f32);
            }
          } else {
            unsigned long long rin =
                (unsigned long long)(((b * 16 + ud) * 64 + uh) * 64 + uw);
            const __hip_bfloat16* i1 = y1 + rin * 64ull;
            unsigned long long i2 = rin * 64ull;
            for (int ci = 0; ci < 64; ++ci) {
              float xf = __bfloat162float(i1[ci]);
              unsigned long long wo = wp + (unsigned long long)ci * 64ull;
              a0 += xf * ldin(w, wo, f32);
              a1 += xf * ldin(w, wo + 1, f32);
              a2 += xf * ldin(w, wo + 2, f32);
              a3 += xf * ldin(w, wo + 3, f32);
            }
            for (int ci = 0; ci < 64; ++ci) {
              float xf = ldin(skip, i2 + ci, f32);
              unsigned long long wo = wp + (unsigned long long)(64 + ci) * 64ull;
              a0 += xf * ldin(w, wo, f32);
              a1 += xf * ldin(w, wo + 1, f32);
              a2 += xf * ldin(w, wo + 2, f32);
              a3 += xf * ldin(w, wo + 3, f32);
            }
          }
        }
      }
    }
    unsigned long long op = (unsigned long long)s * 64ull + c0;
    if (phase == 1) {
      y1[op]     = __float2bfloat16(a0);
      y1[op + 1] = __float2bfloat16(a1);
      y1[op + 2] = __float2bfloat16(a2);
      y1[op + 3] = __float2bfloat16(a3);
    } else {
      stout(out, op, a0, f32);
      stout(out, op + 1, a1, f32);
      stout(out, op + 2, a2, f32);
      stout(out, op + 3, a3, f32);
    }
    return;
  }

  if (phase == 2 || phase == 6) {  // stats: 1024 blocks x 256 threads
    if (fl >= 2) return;
    int f32 = fl;
    float* st = (phase == 2) ? stats : (stats + 128);
    int c = tid & 63;
    int r0 = blockIdx.x * 4 + (tid >> 6);
    float sum = 0.f, ss = 0.f;
    for (int r = r0; r < 262144; r += 4096) {
      unsigned long long idx = (unsigned long long)r * 64ull + c;
      float v = (phase == 2) ? __bfloat162float(y1[idx]) : ldin(out, idx, f32);
      sum += v; ss += v * v;
    }
    atomicAdd(&st[c], sum);
    atomicAdd(&st[64 + c], ss);
    return;
  }

  if (phase == 3 || phase == 7) {  // finalize: 1 block x 64 threads
    if (fl >= 2) return;
    int f32 = fl;
    float* st = (phase == 3) ? stats : (stats + 128);
    const void* gm = (phase == 3) ? g1 : g2;
    const void* bt = (phase == 3) ? b1 : b2;
    int c = tid;
    float invN = 1.f / 262144.f;
    float mean = st[c] * invN;
    float var  = st[64 + c] * invN - mean * mean;
    float sc = ldin(gm, c, f32) * rsqrtf(var + 1e-3f);
    float bi = ldin(bt, c, f32) - mean * sc;
    st[c] = sc;
    st[64 + c] = bi;
    return;
  }

  if (phase == 4) {  // bn+relu in place on y1 (bf16): 65536 x 256
    if (fl >= 2) return;
    unsigned long long i = (unsigned long long)blockIdx.x * 256 + tid;
    int c = (int)(i & 63ull);
    float f = stats[c] * __bfloat162float(y1[i]) + stats[64 + c];
    y1[i] = __float2bfloat16(f > 0.f ? f : 0.f);
    return;
  }

  if (phase == 8) {  // final bn+relu on out (dtype per flag) or fp32 sentinel
    unsigned long long i = (unsigned long long)blockIdx.x * 256 + tid;
    if (fl >= 2) {
      ((float*)out)[i] = (fl == 2) ? 0.25f : 0.75f;
      return;
    }
    int f32 = fl;
    const float* st = stats + 128;
    int c = (int)(i & 63ull);
    float f = st[c] * ldin(out, i, f32) + st[64 + c];
    stout(out, i, f > 0.f ? f : 0.f, f32);
    return;
  }
}

extern "C" void kernel_launch(void* const* d_in, const int* in_sizes, int n_in,
                              void* d_out, int out_size, void* d_ws, size_t ws_size,
                              hipStream_t stream) {
  (void)out_size;
  // slot mapping from in_sizes (constant per session -> capture-safe)
  // insertion order: x,w1,w2,skip,gamma1,beta1,gamma2,beta2,training
  // sorted-key order: beta1,beta2,gamma1,gamma2,skip,training,w1,w2,x
  int ix = 0, iw1 = 1, iw2 = 2, isk = 3, ig1 = 4, ib1 = 5, ig2 = 6, ib2 = 7;
  int force = 0;
  if (n_in >= 9 && in_sizes[0] == 4194304 && in_sizes[1] == 884736 &&
      in_sizes[3] == 16777216 && in_sizes[4] == 64) {
    // insertion order (defaults)
  } else if (n_in >= 9 && in_sizes[0] == 64 && in_sizes[4] == 16777216 &&
             in_sizes[6] == 884736 && in_sizes[8] == 4194304) {
    ib1 = 0; ib2 = 1; ig1 = 2; ig2 = 3; isk = 4; iw1 = 6; iw2 = 7; ix = 8;
  } else {
    force = 3;
  }
  if (ws_size < (32ull << 20) + 2048ull) force = 3;

  __hip_bfloat16* y1 = (__hip_bfloat16*)d_ws;
  float* stats = (float*)((char*)d_ws + (32ull << 20));
  int* flag = (int*)((char*)d_ws + (32ull << 20) + 1024ull);
  if (ws_size < 2048ull) { stats = (float*)d_ws; flag = (int*)((char*)d_ws + 1024ull); }

  const void* X  = d_in[ix];
  const void* W1 = d_in[iw1];
  const void* W2 = d_in[iw2];
  const void* SK = d_in[isk];
  const void* G1 = d_in[ig1];
  const void* B1 = d_in[ib1];
  const void* G2 = d_in[ig2];
  const void* B2 = d_in[ib2];

#define HG_LAUNCH(ph, nb, nt) \
  HyperGANUpBlock_47287589929740_kernel<<<nb, nt, 0, stream>>>( \
      ph, force, X, W1, W2, SK, G1, B1, G2, B2, y1, d_out, stats, flag)

  HG_LAUNCH(0, 1, 256);        // init stats + dtype flag
  HG_LAUNCH(1, 16384, 256);    // conv1 -> y1 (bf16, ws)
  HG_LAUNCH(2, 1024, 256);     // stats(y1)
  HG_LAUNCH(3, 1, 64);         // finalize BN1
  HG_LAUNCH(4, 65536, 256);    // bn+relu y1
  HG_LAUNCH(5, 16384, 256);    // conv2 -> out (dtype per flag)
  HG_LAUNCH(6, 1024, 256);     // stats(out)
  HG_LAUNCH(7, 1, 64);         // finalize BN2
  HG_LAUNCH(8, 65536, 256);    // bn+relu out / sentinel
#undef HG_LAUNCH
}

// Round 8
// 1226.653 us; speedup vs baseline: 78.7610x; 78.7610x over previous
//
#include <hip/hip_runtime.h>

// HyperGANUpBlock (all I/O fp32 — verified R7):
// x[4,8,32,32,128] -> up2 -> conv3^3(128->64, per-sample w1) -> BN(train,1e-3)+ReLU
// -> concat skip[4,16,64,64,64] -> conv3^3(128->64, per-sample w2) -> BN+ReLU -> out fp32.
// ROWS = 262144, 64 ch. MFMA implicit GEMM: 27 taps x K=128, mfma_f32_16x16x32_bf16.
// ws: [0,32MiB) y1 bf16 (raw conv1 out, then bn+relu'd in place); +32MiB: float sums[512].

typedef __attribute__((ext_vector_type(8))) short short8;
typedef __attribute__((ext_vector_type(4))) float f32x4;

__device__ __forceinline__ float bf2f(unsigned short u) {
  union { unsigned int i; float f; } v; v.i = ((unsigned int)u) << 16; return v.f;
}
__device__ __forceinline__ unsigned short f2b(float f) {
  union { float ff; unsigned int u; } v; v.ff = f;
  unsigned int x = v.u;
  return (unsigned short)((x + 0x7FFFu + ((x >> 16) & 1u)) >> 16);  // RNE
}
__device__ __forceinline__ unsigned int pk2(float a, float b) {
  return (unsigned int)f2b(a) | ((unsigned int)f2b(b) << 16);
}

#define ASTR 136  // A-tile LDS row stride (bf16): 272 B, 16B-aligned, 2-way-free reads
#define WSTR 132  // W-tile LDS row stride (bf16): 264 B, 8B-aligned, 4-way writes

// mode 0: conv1 (src = x fp32, upsample addressing) -> outb (y1 raw bf16)
// mode 1: conv2 (src = [y1n bf16 | skip fp32])      -> outf (d_out raw fp32)
__global__ __launch_bounds__(256) void hg_conv_mfma_k(
    const float* __restrict__ xf, const unsigned short* __restrict__ y1n,
    const float* __restrict__ skip, const float* __restrict__ w,
    unsigned short* __restrict__ outb, float* __restrict__ outf, int mode) {
  __shared__ short Al[128 * ASTR];  // 34816 B
  __shared__ short Wl[64 * WSTR];   // 16896 B
  int tid = threadIdx.x;
  int m0 = blockIdx.x << 7;         // first output row of this block
  int b   = m0 >> 16;
  int od  = (m0 >> 12) & 15;
  int oh0 = (m0 >> 6) & 63;         // block covers oh0, oh0+1 (128 rows, same b/od)
  int lane = tid & 63;
  int quad = lane >> 4;
  int l16  = lane & 15;
  int wm   = (tid >> 6) << 5;       // wave's row offset: 0/32/64/96

  f32x4 acc[2][4];
  for (int i = 0; i < 2; ++i)
    for (int j = 0; j < 4; ++j) acc[i][j] = (f32x4){0.f, 0.f, 0.f, 0.f};

  const float* wb = w + (size_t)b * 27 * 8192;
  int wco = tid & 63;
  int wg  = tid >> 6;
  int chunk = tid & 15;
  int rb    = tid >> 4;

  for (int tap = 0; tap < 27; ++tap) {
    int kd = tap / 9;
    int kh = (tap / 3) % 3;
    int kw = tap % 3;
    int ud = od + kd - 1;
    int dok = (ud >= 0 && ud < 16);

    // ---- stage W: w[b][tap][ci][co] fp32 -> Wl[co][ci] bf16 (transpose) ----
    {
      const float* wp = wb + (size_t)tap * 8192 + wco;
      int ci0 = wg << 5;
      for (int c = 0; c < 32; c += 2) {
        float f0 = wp[(size_t)(ci0 + c) * 64];
        float f1 = wp[(size_t)(ci0 + c + 1) * 64];
        *(unsigned int*)&Wl[wco * WSTR + ci0 + c] = pk2(f0, f1);
      }
    }
    // ---- stage A: 128 rows x 128 ch bf16; zero padding for invalid taps ----
    for (int i = 0; i < 8; ++i) {
      int r  = rb + (i << 4);
      int ow = r & 63;
      int g  = r >> 6;
      int uh = oh0 + g + kh - 1;
      int uw = ow + kw - 1;
      uint4 val = make_uint4(0u, 0u, 0u, 0u);
      if (dok && uh >= 0 && uh < 64 && uw >= 0 && uw < 64) {
        if (mode == 0) {
          size_t src = ((((size_t)(b * 8 + (ud >> 1))) * 32 + (uh >> 1)) * 32 +
                        (uw >> 1)) * 128 + (chunk << 3);
          float4 f0 = *(const float4*)(xf + src);
          float4 f1 = *(const float4*)(xf + src + 4);
          val.x = pk2(f0.x, f0.y); val.y = pk2(f0.z, f0.w);
          val.z = pk2(f1.x, f1.y); val.w = pk2(f1.z, f1.w);
        } else {
          size_t srow = (((size_t)(b * 16 + ud)) * 64 + uh) * 64 + uw;
          if (chunk < 8) {
            val = *(const uint4*)(y1n + srow * 64 + (chunk << 3));
          } else {
            const float* sp = skip + srow * 64 + ((chunk - 8) << 3);
            float4 f0 = *(const float4*)(sp);
            float4 f1 = *(const float4*)(sp + 4);
            val.x = pk2(f0.x, f0.y); val.y = pk2(f0.z, f0.w);
            val.z = pk2(f1.x, f1.y); val.w = pk2(f1.z, f1.w);
          }
        }
      }
      *(uint4*)&Al[r * ASTR + (chunk << 3)] = val;  // 16B-aligned ds_write_b128
    }
    __syncthreads();

    // ---- MFMA: 4 k-steps x (2 m-tiles x 4 n-tiles) ----
    for (int k0 = 0; k0 < 128; k0 += 32) {
      int kk = k0 + (quad << 3);
      union { uint4 u; short8 s; } cv;
      short8 av[2];
      cv.u = *(const uint4*)&Al[(wm + l16) * ASTR + kk];       av[0] = cv.s;
      cv.u = *(const uint4*)&Al[(wm + 16 + l16) * ASTR + kk];  av[1] = cv.s;
      short8 bv[4];
      for (int nt = 0; nt < 4; ++nt) {
        int base = ((nt << 4) + l16) * WSTR + kk;
        uint2 lo = *(const uint2*)&Wl[base];
        uint2 hi = *(const uint2*)&Wl[base + 4];
        cv.u = make_uint4(lo.x, lo.y, hi.x, hi.y);
        bv[nt] = cv.s;
      }
      for (int mt = 0; mt < 2; ++mt)
        for (int nt = 0; nt < 4; ++nt)
          acc[mt][nt] = __builtin_amdgcn_mfma_f32_16x16x32_bf16(
              av[mt], bv[nt], acc[mt][nt], 0, 0, 0);
    }
    __syncthreads();
  }

  // ---- epilogue: C/D layout row = quad*4+reg, col = lane&15 ----
  for (int mt = 0; mt < 2; ++mt) {
    int mbase = m0 + wm + (mt << 4) + (quad << 2);
    for (int nt = 0; nt < 4; ++nt) {
      int n = (nt << 4) + l16;
      for (int r = 0; r < 4; ++r) {
        float v = acc[mt][nt][r];
        size_t o = (size_t)(mbase + r) * 64 + n;
        if (mode == 0) outb[o] = f2b(v);
        else outf[o] = v;
      }
    }
  }
}

__global__ void hg_zero_k(float* __restrict__ p) {
  p[threadIdx.x] = 0.f;
  p[threadIdx.x + 256] = 0.f;
}

// per-channel sum/sumsq over 262144 rows x 64 ch; isf: fp32 src else bf16 src
__global__ __launch_bounds__(256) void hg_stats_k(const unsigned short* __restrict__ yb,
                                                  const float* __restrict__ yf, int isf,
                                                  float* __restrict__ sums) {
  int t = threadIdx.x;
  int c = t & 63;
  int r0 = blockIdx.x * 4 + (t >> 6);
  float sum = 0.f, ss = 0.f;
  for (int r = r0; r < 262144; r += 4096) {
    size_t idx = (size_t)r * 64 + c;
    float v = isf ? yf[idx] : bf2f(yb[idx]);
    sum += v; ss += v * v;
  }
  atomicAdd(&sums[c], sum);
  atomicAdd(&sums[64 + c], ss);
}

__global__ void hg_fin_k(float* __restrict__ sb, const float* __restrict__ gm,
                         const float* __restrict__ bt) {
  int c = threadIdx.x;  // 64
  float invN = 1.f / 262144.f;
  float mean = sb[c] * invN;
  float var  = sb[64 + c] * invN - mean * mean;
  float sc = gm[c] * rsqrtf(var + 1e-3f);
  sb[c] = sc;
  sb[64 + c] = bt[c] - mean * sc;
}

// in-place BN+ReLU on y1 (bf16), 8 elems per thread
__global__ __launch_bounds__(256) void hg_bnrelu_b_k(unsigned short* __restrict__ y,
                                                     const float* __restrict__ sb) {
  size_t i = (size_t)blockIdx.x * 256 + threadIdx.x;  // uint4 index, 2097152 total
  int c8 = ((int)i & 7) << 3;
  uint4 v = *(uint4*)(y + i * 8);
  unsigned int u[4] = {v.x, v.y, v.z, v.w};
  unsigned int o[4];
  for (int q = 0; q < 4; ++q) {
    int c = c8 + q * 2;
    float f0 = sb[c] * bf2f((unsigned short)(u[q] & 0xFFFFu)) + sb[64 + c];
    float f1 = sb[c + 1] * bf2f((unsigned short)(u[q] >> 16)) + sb[64 + c + 1];
    o[q] = pk2(f0 > 0.f ? f0 : 0.f, f1 > 0.f ? f1 : 0.f);
  }
  *(uint4*)(y + i * 8) = make_uint4(o[0], o[1], o[2], o[3]);
}

// in-place BN+ReLU on out (fp32), 4 elems per thread
__global__ __launch_bounds__(256) void hg_bnrelu_f_k(float* __restrict__ y,
                                                     const float* __restrict__ sb) {
  size_t i = (size_t)blockIdx.x * 256 + threadIdx.x;  // float4 index, 4194304 total
  int c4 = ((int)i & 15) << 2;
  float4 v = *(float4*)(y + i * 4);
  float f;
  f = sb[c4]     * v.x + sb[64 + c4];     v.x = f > 0.f ? f : 0.f;
  f = sb[c4 + 1] * v.y + sb[64 + c4 + 1]; v.y = f > 0.f ? f : 0.f;
  f = sb[c4 + 2] * v.z + sb[64 + c4 + 2]; v.z = f > 0.f ? f : 0.f;
  f = sb[c4 + 3] * v.w + sb[64 + c4 + 3]; v.w = f > 0.f ? f : 0.f;
  *(float4*)(y + i * 4) = v;
}

extern "C" void kernel_launch(void* const* d_in, const int* in_sizes, int n_in,
                              void* d_out, int out_size, void* d_ws, size_t ws_size,
                              hipStream_t stream) {
  (void)out_size;
  // slot mapping (insertion order vs sorted-key order), constant per session
  int ix = 0, iw1 = 1, iw2 = 2, isk = 3, ig1 = 4, ib1 = 5, ig2 = 6, ib2 = 7;
  if (n_in >= 9 && in_sizes[0] == 4194304 && in_sizes[1] == 884736 &&
      in_sizes[3] == 16777216 && in_sizes[4] == 64) {
    // insertion order
  } else if (n_in >= 9 && in_sizes[0] == 64 && in_sizes[4] == 16777216 &&
             in_sizes[6] == 884736 && in_sizes[8] == 4194304) {
    ib1 = 0; ib2 = 1; ig1 = 2; ig2 = 3; isk = 4; iw1 = 6; iw2 = 7; ix = 8;
  } else {
    return;  // unrecognized -> leave output zero (fails loudly)
  }
  if (ws_size < (32ull << 20) + 2048ull) return;

  const float* x    = (const float*)d_in[ix];
  const float* w1   = (const float*)d_in[iw1];
  const float* w2   = (const float*)d_in[iw2];
  const float* skip = (const float*)d_in[isk];
  const float* g1   = (const float*)d_in[ig1];
  const float* b1   = (const float*)d_in[ib1];
  const float* g2   = (const float*)d_in[ig2];
  const float* b2   = (const float*)d_in[ib2];

  unsigned short* y1 = (unsigned short*)d_ws;                 // 32 MiB bf16
  float* sums  = (float*)((char*)d_ws + (32ull << 20));
  float* sums1 = sums;
  float* sums2 = sums + 128;
  float* out = (float*)d_out;

  hg_zero_k<<<1, 256, 0, stream>>>(sums);
  hg_conv_mfma_k<<<2048, 256, 0, stream>>>(x, y1, skip, w1, y1, out, 0);  // conv1 -> y1 raw
  hg_stats_k<<<1024, 256, 0, stream>>>(y1, out, 0, sums1);
  hg_fin_k<<<1, 64, 0, stream>>>(sums1, g1, b1);
  hg_bnrelu_b_k<<<8192, 256, 0, stream>>>(y1, sums1);                     // y1 normalized
  hg_conv_mfma_k<<<2048, 256, 0, stream>>>(x, y1, skip, w2, y1, out, 1);  // conv2 -> out raw
  hg_stats_k<<<1024, 256, 0, stream>>>(y1, out, 1, sums2);
  hg_fin_k<<<1, 64, 0, stream>>>(sums2, g2, b2);
  hg_bnrelu_f_k<<<16384, 256, 0, stream>>>(out, sums2);
}

// Round 9
// 784.879 us; speedup vs baseline: 123.0920x; 1.5629x over previous
//
#include <hip/hip_runtime.h>

// HyperGANUpBlock (all fp32 I/O): x[4,8,32,32,128] -> up2 -> conv3^3(128->64, per-sample
// w1) -> BN(train,1e-3)+ReLU -> concat skip -> conv3^3(128->64, per-sample w2) -> BN+ReLU.
// ROWS = 262144. MFMA implicit GEMM, mfma_f32_16x16x32_bf16, 27 taps x K=128.
// R9: XCD swizzle (b = xcd&3: per-XCD L2 keeps one sample's weights+activations resident),
// pre-transposed bf16 weights in ws (guarded), A-halo staged per (kd,kh) (9 stages not 27),
// BN1+ReLU folded into conv2 staging.
// ws: [0,32Mi) y1 bf16 | +32Mi: float sums[512] | +32Mi+2Ki: wt1, wt2 (bf16 [b][tap][co][ci]).

typedef __attribute__((ext_vector_type(8))) short short8;
typedef __attribute__((ext_vector_type(4))) float f32x4;

__device__ __forceinline__ float bf2f(unsigned short u) {
  union { unsigned int i; float f; } v; v.i = ((unsigned int)u) << 16; return v.f;
}
__device__ __forceinline__ unsigned short f2b(float f) {
  union { float ff; unsigned int u; } v; v.ff = f;
  unsigned int x = v.u;
  return (unsigned short)((x + 0x7FFFu + ((x >> 16) & 1u)) >> 16);  // RNE
}
__device__ __forceinline__ unsigned int pk2(float a, float b) {
  return (unsigned int)f2b(a) | ((unsigned int)f2b(b) << 16);
}

#define ASTR 136  // A-halo row stride (shorts): 272 B, 16B-aligned
#define WSTR 132  // W row stride (shorts): 264 B, 8B-aligned

// w[b,tap,ci,co] fp32 -> wt[b,tap,co,ci] bf16 ; 216 blocks (108 per tensor)
__global__ __launch_bounds__(256) void hg_wt_k(const float* __restrict__ w1,
                                               const float* __restrict__ w2,
                                               unsigned short* __restrict__ wt1,
                                               unsigned short* __restrict__ wt2) {
  __shared__ short T[64 * ASTR];
  int blk = blockIdx.x;
  int sel = blk >= 108;
  const float* w = sel ? w2 : w1;
  unsigned short* wt = sel ? wt2 : wt1;
  int bt = sel ? blk - 108 : blk;
  const float* src = w + (size_t)bt * 8192;
  int tid = threadIdx.x;
  int co = tid & 63;
  int c0 = tid >> 6;
  for (int i = 0; i < 32; ++i) {
    int ci = c0 + (i << 2);
    T[co * ASTR + ci] = (short)f2b(src[(size_t)ci * 64 + co]);
  }
  __syncthreads();
  unsigned short* dst = wt + (size_t)bt * 8192;
  for (int i = 0; i < 4; ++i) {
    int task = tid + (i << 8);          // 1024 tasks
    int row = task >> 4, q = task & 15;
    *(uint4*)(dst + row * 128 + (q << 3)) = *(const uint4*)&T[row * ASTR + (q << 3)];
  }
}

// mode 0: conv1 (x fp32 upsampled) -> outb bf16 raw
// mode 1: conv2 ([bn1relu(y1) | skip]) -> outf fp32 raw
__global__ __launch_bounds__(256) void hg_conv_k(
    const float* __restrict__ xf, const unsigned short* __restrict__ y1n,
    const float* __restrict__ skip, const float* __restrict__ wf,
    const unsigned short* __restrict__ wt, const float* __restrict__ bn,
    unsigned short* __restrict__ outb, float* __restrict__ outf,
    int mode, int has_wt) {
  __shared__ short Al[132 * ASTR];  // 35904 B: 2 uh-rows x 66 uw x 128 ch
  __shared__ short Wl[64 * WSTR];   // 16896 B
  __shared__ float sbl[128];
  int tid = threadIdx.x;
  // XCD-aware swizzle: blocks on one XCD share b (round-robin dispatch heuristic)
  int xcd = blockIdx.x & 7, slot = blockIdx.x >> 3;
  int b = xcd & 3;
  int t = ((xcd >> 2) << 8) + slot;       // 0..511 tile within sample
  int m0 = (b << 16) + (t << 7);
  int od  = (t >> 5) & 15;
  int oh0 = (t << 1) & 63;
  int lane = tid & 63, quad = lane >> 4, l16 = lane & 15;
  int wm = (tid >> 6) << 5;               // wave row offset 0/32/64/96

  if (mode == 1 && tid < 128) sbl[tid] = bn[tid];

  f32x4 acc[2][4];
  for (int i = 0; i < 2; ++i)
    for (int j = 0; j < 4; ++j) acc[i][j] = (f32x4){0.f, 0.f, 0.f, 0.f};

  const float* wbf = wf + (size_t)b * 27 * 8192;
  const unsigned short* wbt = wt + (size_t)b * 27 * 8192;

  for (int kd = 0; kd < 3; ++kd) {
    int ud = od + kd - 1;
    int dok = (ud >= 0 && ud < 16);
    for (int kh = 0; kh < 3; ++kh) {
      __syncthreads();  // prior MFMAs done before Al/Wl overwrite (also covers sbl init)
      // ---- stage A halo: 2 x 66 x 128, zero padding ----
      for (int i = 0; i < 9; ++i) {
        int task = tid + (i << 8);
        if (task < 2112) {
          int chunk = task & 15;
          int pos = task >> 4;            // 0..131
          int g = (pos >= 66) ? 1 : 0;
          int uwi = pos - (g ? 66 : 0);
          int uh = oh0 + g + kh - 1;
          int uw = uwi - 1;
          uint4 val = make_uint4(0u, 0u, 0u, 0u);
          if (dok && (unsigned)uh < 64u && (unsigned)uw < 64u) {
            if (mode == 0) {
              size_t src = ((((size_t)(b * 8 + (ud >> 1))) * 32 + (uh >> 1)) * 32 +
                            (uw >> 1)) * 128 + (chunk << 3);
              float4 f0 = *(const float4*)(xf + src);
              float4 f1 = *(const float4*)(xf + src + 4);
              val.x = pk2(f0.x, f0.y); val.y = pk2(f0.z, f0.w);
              val.z = pk2(f1.x, f1.y); val.w = pk2(f1.z, f1.w);
            } else {
              size_t srow = (((size_t)(b * 16 + ud)) * 64 + uh) * 64 + uw;
              if (chunk < 8) {
                uint4 raw = *(const uint4*)(y1n + srow * 64 + (chunk << 3));
                unsigned int u[4] = {raw.x, raw.y, raw.z, raw.w};
                unsigned int o[4];
                int c0 = chunk << 3;
                for (int q = 0; q < 4; ++q) {
                  int c = c0 + q * 2;
                  float f0 = sbl[c] * bf2f((unsigned short)(u[q] & 0xFFFFu)) + sbl[64 + c];
                  float f1 = sbl[c + 1] * bf2f((unsigned short)(u[q] >> 16)) + sbl[64 + c + 1];
                  o[q] = pk2(f0 > 0.f ? f0 : 0.f, f1 > 0.f ? f1 : 0.f);
                }
                val = make_uint4(o[0], o[1], o[2], o[3]);
              } else {
                const float* sp = skip + srow * 64 + ((chunk - 8) << 3);
                float4 f0 = *(const float4*)(sp);
                float4 f1 = *(const float4*)(sp + 4);
                val.x = pk2(f0.x, f0.y); val.y = pk2(f0.z, f0.w);
                val.z = pk2(f1.x, f1.y); val.w = pk2(f1.z, f1.w);
              }
            }
          }
          *(uint4*)&Al[pos * ASTR + (chunk << 3)] = val;
        }
      }
      for (int kw = 0; kw < 3; ++kw) {
        if (kw) __syncthreads();  // prior MFMAs done before Wl overwrite
        int tap = (kd * 3 + kh) * 3 + kw;
        if (has_wt) {
          const unsigned short* wsrc = wbt + (size_t)tap * 8192;
          for (int i = 0; i < 4; ++i) {
            int task = tid + (i << 8);    // 1024 tasks
            int co = task >> 4, q = task & 15;
            *(uint4*)&Wl[co * WSTR + (q << 3)] = *(const uint4*)(wsrc + co * 128 + (q << 3));
          }
        } else {
          const float* wp = wbf + (size_t)tap * 8192 + (tid & 63);
          int wco = tid & 63;
          int ci0 = (tid >> 6) << 5;
          for (int c = 0; c < 32; c += 2) {
            float f0 = wp[(size_t)(ci0 + c) * 64];
            float f1 = wp[(size_t)(ci0 + c + 1) * 64];
            *(unsigned int*)&Wl[wco * WSTR + ci0 + c] = pk2(f0, f1);
          }
        }
        __syncthreads();
        // ---- MFMA: 4 k-steps x (2 m-tiles x 4 n-tiles) ----
        for (int k0 = 0; k0 < 128; k0 += 32) {
          int kk = k0 + (quad << 3);
          union { uint4 u; short8 s; } cv;
          short8 av[2];
          for (int mt = 0; mt < 2; ++mt) {
            int r = wm + (mt << 4) + l16;
            int g = r >> 6, ow = r & 63;
            cv.u = *(const uint4*)&Al[(g * 66 + ow + kw) * ASTR + kk];
            av[mt] = cv.s;
          }
          short8 bv[4];
          for (int nt = 0; nt < 4; ++nt) {
            int base = ((nt << 4) + l16) * WSTR + kk;
            uint2 lo = *(const uint2*)&Wl[base];
            uint2 hi = *(const uint2*)&Wl[base + 4];
            cv.u = make_uint4(lo.x, lo.y, hi.x, hi.y);
            bv[nt] = cv.s;
          }
          for (int mt = 0; mt < 2; ++mt)
            for (int nt = 0; nt < 4; ++nt)
              acc[mt][nt] = __builtin_amdgcn_mfma_f32_16x16x32_bf16(
                  av[mt], bv[nt], acc[mt][nt], 0, 0, 0);
        }
      }
    }
  }

  // epilogue: C/D row = quad*4+reg, col = lane&15
  for (int mt = 0; mt < 2; ++mt) {
    int mbase = m0 + wm + (mt << 4) + (quad << 2);
    for (int nt = 0; nt < 4; ++nt) {
      int n = (nt << 4) + l16;
      for (int r = 0; r < 4; ++r) {
        float v = acc[mt][nt][r];
        size_t o = (size_t)(mbase + r) * 64 + n;
        if (mode == 0) outb[o] = f2b(v);
        else outf[o] = v;
      }
    }
  }
}

__global__ void hg_zero_k(float* __restrict__ p) {
  p[threadIdx.x] = 0.f;
  p[threadIdx.x + 256] = 0.f;
}

__global__ __launch_bounds__(256) void hg_stats_k(const unsigned short* __restrict__ yb,
                                                  const float* __restrict__ yf, int isf,
                                                  float* __restrict__ sums) {
  int t = threadIdx.x;
  int c = t & 63;
  int r0 = blockIdx.x * 4 + (t >> 6);
  float sum = 0.f, ss = 0.f;
  for (int r = r0; r < 262144; r += 4096) {
    size_t idx = (size_t)r * 64 + c;
    float v = isf ? yf[idx] : bf2f(yb[idx]);
    sum += v; ss += v * v;
  }
  atomicAdd(&sums[c], sum);
  atomicAdd(&sums[64 + c], ss);
}

__global__ void hg_fin_k(float* __restrict__ sb, const float* __restrict__ gm,
                         const float* __restrict__ bt) {
  int c = threadIdx.x;  // 64
  float invN = 1.f / 262144.f;
  float mean = sb[c] * invN;
  float var  = sb[64 + c] * invN - mean * mean;
  float sc = gm[c] * rsqrtf(var + 1e-3f);
  sb[c] = sc;
  sb[64 + c] = bt[c] - mean * sc;
}

__global__ __launch_bounds__(256) void hg_bnrelu_f_k(float* __restrict__ y,
                                                     const float* __restrict__ sb) {
  size_t i = (size_t)blockIdx.x * 256 + threadIdx.x;  // float4 index
  int c4 = ((int)i & 15) << 2;
  float4 v = *(float4*)(y + i * 4);
  float f;
  f = sb[c4]     * v.x + sb[64 + c4];     v.x = f > 0.f ? f : 0.f;
  f = sb[c4 + 1] * v.y + sb[64 + c4 + 1]; v.y = f > 0.f ? f : 0.f;
  f = sb[c4 + 2] * v.z + sb[64 + c4 + 2]; v.z = f > 0.f ? f : 0.f;
  f = sb[c4 + 3] * v.w + sb[64 + c4 + 3]; v.w = f > 0.f ? f : 0.f;
  *(float4*)(y + i * 4) = v;
}

extern "C" void kernel_launch(void* const* d_in, const int* in_sizes, int n_in,
                              void* d_out, int out_size, void* d_ws, size_t ws_size,
                              hipStream_t stream) {
  (void)out_size;
  int ix = 0, iw1 = 1, iw2 = 2, isk = 3, ig1 = 4, ib1 = 5, ig2 = 6, ib2 = 7;
  if (n_in >= 9 && in_sizes[0] == 4194304 && in_sizes[1] == 884736 &&
      in_sizes[3] == 16777216 && in_sizes[4] == 64) {
    // insertion order
  } else if (n_in >= 9 && in_sizes[0] == 64 && in_sizes[4] == 16777216 &&
             in_sizes[6] == 884736 && in_sizes[8] == 4194304) {
    ib1 = 0; ib2 = 1; ig1 = 2; ig2 = 3; isk = 4; iw1 = 6; iw2 = 7; ix = 8;
  } else {
    return;
  }
  if (ws_size < (32ull << 20) + 2048ull) return;

  const float* x    = (const float*)d_in[ix];
  const float* w1   = (const float*)d_in[iw1];
  const float* w2   = (const float*)d_in[iw2];
  const float* skip = (const float*)d_in[isk];
  const float* g1   = (const float*)d_in[ig1];
  const float* b1   = (const float*)d_in[ib1];
  const float* g2   = (const float*)d_in[ig2];
  const float* b2   = (const float*)d_in[ib2];

  unsigned short* y1 = (unsigned short*)d_ws;                     // 32 MiB bf16
  float* sums  = (float*)((char*)d_ws + (32ull << 20));           // 512 floats
  float* sums1 = sums;
  float* sums2 = sums + 128;
  unsigned short* wt1 = (unsigned short*)((char*)d_ws + (32ull << 20) + 2048ull);
  unsigned short* wt2 = wt1 + 884736ull;
  const size_t WS_NEED = (32ull << 20) + 2048ull + 2ull * 884736ull * 2ull;
  int has_wt = (ws_size >= WS_NEED) ? 1 : 0;
  float* out = (float*)d_out;

  hg_zero_k<<<1, 256, 0, stream>>>(sums);
  if (has_wt) hg_wt_k<<<216, 256, 0, stream>>>(w1, w2, wt1, wt2);
  hg_conv_k<<<2048, 256, 0, stream>>>(x, y1, skip, w1, wt1, sums1, y1, out, 0, has_wt);
  hg_stats_k<<<1024, 256, 0, stream>>>(y1, out, 0, sums1);
  hg_fin_k<<<1, 64, 0, stream>>>(sums1, g1, b1);
  hg_conv_k<<<2048, 256, 0, stream>>>(x, y1, skip, w2, wt2, sums1, y1, out, 1, has_wt);
  hg_stats_k<<<1024, 256, 0, stream>>>(y1, out, 1, sums2);
  hg_fin_k<<<1, 64, 0, stream>>>(sums2, g2, b2);
  hg_bnrelu_f_k<<<16384, 256, 0, stream>>>(out, sums2);
}